// Round 16
// baseline (53.880 us; speedup 1.0000x reference)
//
#include <hip/hip_runtime.h>
#include <stdint.h>

// out[b,p] = mean_d( probes[p,d] <= X[b,d] ? 1.0 : X[b,d] )
// B=2048, P=512, D=256, f32. Exact-mask math (validated R6-R13):
//   Y = 1-x (exact), Q1 = K(1-p)+1 (exact int, K=2^24)
//   m = clamp(pk_fma(y, -K, q1)) = clamp(K(x-p)+1) in {0,1}, 1 iff p<=x
//   acc += m*y ; group partial = (32 - Sum y) + Sum m*y ; out = Sum/256
// R16: asm-pinned wave-level LDS pipeline (T3/T4 2-phase for LDS).
//   Explicit ds_read_b128 into named A/B banks; issue bank(s+1) BEFORE
//   computing bank(s); one lgkmcnt(0)+sched_barrier(0) per half-step --
//   the wait trails its loads by a full 576-cyc compute block, so the
//   144-cyc LDS burst hides. This is the order the compiler provably
//   does not emit from C (R5 null result).
// Geometry: 512 thr (8 waves = 8 d-groups), 64b x 32p block, 8x4 tile,
// 96 KiB LDS, grid 512. Staging swizzle + combine reuse R10/R13 pieces.

#define BATCH  2048
#define NPROBE 512
#define DIM    256
#define KF 16777216.0f

typedef float f4 __attribute__((ext_vector_type(4)));
typedef float f2 __attribute__((ext_vector_type(2)));

static __device__ __forceinline__ unsigned lds_off(const float* p) {
  return (unsigned)(uintptr_t)(const __attribute__((address_space(3))) float*)p;
}

#define LOADS(XQ, PQ, S) do {                                   \
    const unsigned sx_ = 16u * (unsigned)(S);                   \
    _Pragma("unroll")                                           \
    for (int i_ = 0; i_ < 8; ++i_)                              \
      asm volatile("ds_read_b128 %0, %1"                        \
                   : "=v"(XQ[i_]) : "v"(cx[i_] ^ sx_));         \
    _Pragma("unroll")                                           \
    for (int j_ = 0; j_ < 4; ++j_)                              \
      asm volatile("ds_read_b128 %0, %1"                        \
                   : "=v"(PQ[j_]) : "v"(cp[j_] ^ sx_));         \
  } while (0)

#define COMPUTE(XQ, PQ) do {                                    \
    _Pragma("unroll")                                           \
    for (int i_ = 0; i_ < 8; ++i_) {                            \
      f2 ylo = {XQ[i_][0], XQ[i_][1]};                          \
      f2 yhi = {XQ[i_][2], XQ[i_][3]};                          \
      accy2[i_] += ylo;                                         \
      accy2[i_] += yhi;                                         \
      _Pragma("unroll")                                         \
      for (int j_ = 0; j_ < 4; ++j_) {                          \
        f2 plo = {PQ[j_][0], PQ[j_][1]};                        \
        f2 phi = {PQ[j_][2], PQ[j_][3]};                        \
        f2 m_;                                                  \
        asm("v_pk_fma_f32 %0, %1, %2, %3 clamp"                 \
            : "=v"(m_) : "v"(ylo), "v"(mK2), "v"(plo));         \
        asm("v_pk_fma_f32 %0, %1, %2, %0"                       \
            : "+v"(acc2[i_][j_]) : "v"(m_), "v"(ylo));          \
        asm("v_pk_fma_f32 %0, %1, %2, %3 clamp"                 \
            : "=v"(m_) : "v"(yhi), "v"(mK2), "v"(phi));         \
        asm("v_pk_fma_f32 %0, %1, %2, %0"                       \
            : "+v"(acc2[i_][j_]) : "v"(m_), "v"(yhi));          \
      }                                                         \
    }                                                           \
  } while (0)

__global__ __launch_bounds__(512, 2)
void yoneda_kernel(const float* __restrict__ X, const float* __restrict__ Pr,
                   float* __restrict__ out) {
  // [0,16384) floats: Y 64 rows x 256 ; [16384,24576): Q1 32 rows x 256
  __shared__ __align__(128) float lds[24576];   // 96 KiB

  const int tid = threadIdx.x;
  const int b0 = blockIdx.y * 64, p0 = blockIdx.x * 32;

  // ---- stage Y = 1-x, write-side XOR swizzle (slot = (q&56)|((q^r)&7))
  #pragma unroll
  for (int s = 0; s < 8; ++s) {
    int idx = s * 512 + tid;           // quad [0,4096)
    int r = idx >> 6, q = idx & 63;
    int slot = (q & 56) | ((q ^ r) & 7);
    f4 x = *(const f4*)(X + (size_t)(b0 + r) * DIM + 4 * q);
    f4 y;
    #pragma unroll
    for (int e = 0; e < 4; ++e) y[e] = 1.0f - x[e];            // exact
    *(f4*)&lds[r * 256 + 4 * slot] = y;
  }
  // ---- stage Q1 = K(1-p)+1 (exact odd int), same swizzle
  #pragma unroll
  for (int s = 0; s < 4; ++s) {
    int idx = s * 512 + tid;           // quad [0,2048)
    int r = idx >> 6, q = idx & 63;
    int slot = (q & 56) | ((q ^ r) & 7);
    f4 p = *(const f4*)(Pr + (size_t)(p0 + r) * DIM + 4 * q);
    f4 qv;
    #pragma unroll
    for (int e = 0; e < 4; ++e) qv[e] = __builtin_fmaf(p[e], -KF, KF) + 1.0f;
    *(f4*)&lds[16384 + r * 256 + 4 * slot] = qv;
  }

  const int w  = tid >> 6;             // wave = d-group 0..7 (32 d = 8 quads)
  const int tb = (tid >> 3) & 7;       // rows tb+8i, i<8
  const int tp = tid & 7;              // cols tp+8j, j<4

  // byte addrs: addr(step s) = C ^ (16*s); swizzle folded (row&7 == tb / tp)
  unsigned cx[8], cp[4];
  const unsigned lbase = lds_off(lds); // 128-aligned
  #pragma unroll
  for (int i = 0; i < 8; ++i)
    cx[i] = lbase + (tb + 8 * i) * 1024u + w * 128u + 16u * tb;
  #pragma unroll
  for (int j = 0; j < 4; ++j)
    cp[j] = lbase + 65536u + (tp + 8 * j) * 1024u + w * 128u + 16u * tp;

  f2 acc2[8][4], accy2[8];
  #pragma unroll
  for (int i = 0; i < 8; ++i) {
    accy2[i] = (f2){0.0f, 0.0f};
    #pragma unroll
    for (int j = 0; j < 4; ++j) acc2[i][j] = (f2){0.0f, 0.0f};
  }
  const f2 mK2 = {-KF, -KF};
  f4 xqA[8], pqA[4], xqB[8], pqB[4];

  __syncthreads();                     // staging visible (drains lgkm)

  LOADS(xqA, pqA, 0);
  #pragma unroll
  for (int s = 0; s < 8; s += 2) {
    asm volatile("s_waitcnt lgkmcnt(0)");      // bank A (step s) ready
    __builtin_amdgcn_sched_barrier(0);         // rule #18: pin consumers
    if (s + 1 < 8) LOADS(xqB, pqB, s + 1);     // issue next EARLY
    __builtin_amdgcn_sched_barrier(0);
    COMPUTE(xqA, pqA);                         // 576 cyc hides B's 144-cyc LDS
    asm volatile("s_waitcnt lgkmcnt(0)");      // bank B ready (wait ~free)
    __builtin_amdgcn_sched_barrier(0);
    if (s + 2 < 8) LOADS(xqA, pqA, s + 2);
    __builtin_amdgcn_sched_barrier(0);
    COMPUTE(xqB, pqB);
  }

  // ---- combine 8 d-group partials (R13 scheme: idx = row*292 + col*9 + w)
  __syncthreads();                     // all tile reads done
  #pragma unroll
  for (int i = 0; i < 8; ++i) {
    float sxg = 32.0f - (accy2[i][0] + accy2[i][1]);   // Sum_group x
    #pragma unroll
    for (int j = 0; j < 4; ++j) {
      int row = tb + 8 * i, col = tp + 8 * j;
      lds[row * 292 + col * 9 + w] = sxg + acc2[i][j][0] + acc2[i][j][1];
    }
  }
  __syncthreads();
  const float inv = 1.0f / 256.0f;
  #pragma unroll
  for (int k = 0; k < 4; ++k) {
    int o = tid + 512 * k;             // [0,2048)
    int row = o >> 5, col = o & 31;
    int base = row * 292 + col * 9;
    float v = lds[base];
    #pragma unroll
    for (int g = 1; g < 8; ++g) v += lds[base + g];    // ascending -> deterministic
    out[(size_t)(b0 + row) * NPROBE + p0 + col] = v * inv;
  }
}

extern "C" void kernel_launch(void* const* d_in, const int* in_sizes, int n_in,
                              void* d_out, int out_size, void* d_ws, size_t ws_size,
                              hipStream_t stream) {
  const float* X  = (const float*)d_in[0];   // (2048, 256) f32
  const float* Pr = (const float*)d_in[1];   // (512, 256)  f32
  float* outp = (float*)d_out;               // (2048, 512) f32
  dim3 grid(NPROBE / 32, BATCH / 64);        // (16, 32) = 512 blocks
  yoneda_kernel<<<grid, 512, 0, stream>>>(X, Pr, outp);
}